// Round 9
// baseline (102.239 us; speedup 1.0000x reference)
//
#include <hip/hip_runtime.h>
#include <hip/hip_bf16.h>
#include <stdint.h>

// B=4, C=64, N=16384, K=16, CO=64 (fp32 I/O, int32 idx)
// R9 = R8 with k2 occupancy doubled: __launch_bounds__(256,8).
// Rationale: R6 probe measured gather VGPR=64 (fits 8 blocks/CU) but
// occupancy only 34% under the (256,4) bound; k2 is latency-bound
// (VALUBusy 54%, HBM 10%, VALU-cut-insensitive per R7) -> more waves
// per CU is the remaining lever. Everything else identical to R8.
#define NDIM 16384
#define KNB 16
#define BNK_F 1048576.0f

typedef __attribute__((ext_vector_type(8))) short bf16x8_t;
typedef __attribute__((ext_vector_type(4))) float f32x4_t;
typedef __attribute__((ext_vector_type(2))) float f32x2_t;

__device__ inline unsigned pack_bf16(float a, float b) {
    return (unsigned)__bfloat16_as_ushort(__float2bfloat16(a))
         | ((unsigned)__bfloat16_as_ushort(__float2bfloat16(b)) << 16);
}

// ---------------- Kernel 1: MFMA GEMM (R7-proven, unchanged) ----------------
__global__ __launch_bounds__(256) void gemm_mfma_kernel(
    const float* __restrict__ x,            // (B, 64, N)
    const float* __restrict__ W,            // (64, 128)
    unsigned* __restrict__ y1p,             // (B,N,32) bf16-pairs
    unsigned* __restrict__ y2p,             // (B,N,32) bf16-pairs
    float* __restrict__ statsN)             // (32,128) striped stats - zeroed here
{
    __shared__ alignas(16) short lds_a[128 * 72];  // row pad 72 -> 2-way-free b128
    __shared__ alignas(16) short lds_b[64 * 72];   // x tile, n-major

    const int tid = threadIdx.x;
    if (blockIdx.x == 0) {
        for (int i = tid; i < 4096; i += 256) statsN[i] = 0.0f;
    }
    const int b  = blockIdx.x >> 8;
    const int n0 = (blockIdx.x & 255) << 6;

    for (int idx = tid; idx < 1024; idx += 256) {
        const int r = idx >> 4, q = idx & 15;
        const f32x4_t wa = *(const f32x4_t*)&W[r * 128 + q * 4];
        const f32x4_t wb = *(const f32x4_t*)&W[r * 128 + 64 + q * 4];
        const f32x4_t wsum = wa + wb;                  // v_pk_add_f32
        uint2 pa = { pack_bf16(wsum[0], wsum[1]), pack_bf16(wsum[2], wsum[3]) };
        uint2 pb = { pack_bf16(wb[0], wb[1]),     pack_bf16(wb[2], wb[3]) };
        *(uint2*)&lds_a[r * 72 + q * 4]        = pa;
        *(uint2*)&lds_a[(64 + r) * 72 + q * 4] = pb;
    }
    {
        const float* xb = x + (size_t)b * 64 * NDIM + n0;
        const int n = tid & 63;
        unsigned* lb32 = (unsigned*)lds_b;
        for (int cp = tid >> 6; cp < 32; cp += 4) {
            int c = cp * 2;
            float x0 = xb[(size_t)c * NDIM + n];
            float x1 = xb[(size_t)(c + 1) * NDIM + n];
            lb32[n * 36 + cp] = pack_bf16(x0, x1);
        }
    }
    __syncthreads();

    const int lane = tid & 63;
    const int w    = tid >> 6;
    const int m    = lane & 15;
    const int q    = lane >> 4;
    const int n    = w * 16 + m;

    const bf16x8_t b0 = *(const bf16x8_t*)&lds_b[n * 72 + q * 8];
    const bf16x8_t b1 = *(const bf16x8_t*)&lds_b[n * 72 + q * 8 + 32];

    const size_t rowbase = ((size_t)(b * NDIM + n0 + n)) * 32;
    #pragma unroll
    for (int t = 0; t < 8; ++t) {
        const short* ap = &lds_a[(t * 16 + m) * 72 + q * 8];
        bf16x8_t a0 = *(const bf16x8_t*)ap;
        bf16x8_t a1 = *(const bf16x8_t*)(ap + 32);
        f32x4_t acc = {0.f, 0.f, 0.f, 0.f};
        acc = __builtin_amdgcn_mfma_f32_16x16x32_bf16(a0, b0, acc, 0, 0, 0);
        acc = __builtin_amdgcn_mfma_f32_16x16x32_bf16(a1, b1, acc, 0, 0, 0);
        unsigned* dst = (t < 4) ? y1p : y2p;
        uint2 pk = { pack_bf16(acc[0], acc[1]), pack_bf16(acc[2], acc[3]) };
        *(uint2*)&dst[rowbase + (t & 3) * 8 + q * 2] = pk;
    }
}

// ---------------- Kernel 2: gather, vector-idx + bpermute, 8 blocks/CU ----------------
// 2048 blocks x 256, XCD-pinned batches. 32 outstanding gathers/wave (R0 bursts).
__global__ __launch_bounds__(256, 8) void gather_kernel(
    const unsigned* __restrict__ y1p,        // (B,N,32) bf16-pairs
    const unsigned* __restrict__ y2p,
    const int* __restrict__ ei,              // (B, N, 16)
    const float* __restrict__ gamma,
    unsigned* __restrict__ hselp,            // (B,N,32) bf16-pairs
    float* __restrict__ statsN)              // (32,128)
{
    const int tid  = threadIdx.x;
    const int w    = __builtin_amdgcn_readfirstlane(tid >> 6);
    const int lane = tid & 63;
    const int half = lane >> 5;
    const int c2   = lane & 31;
    const int g    = blockIdx.x;
    const int xcd  = g & 7;
    const int b    = xcd >> 1;
    const int row0 = b * NDIM + (xcd & 1) * 8192 + (g >> 3) * 32 + w * 8;

    // 128 wave indices (rows row0..row0+7): 2 coalesced vector loads, issued first
    const int idx0 = ei[(size_t)row0 * KNB + lane];        // rows row0..row0+3
    const int idx1 = ei[(size_t)row0 * KNB + 64 + lane];   // rows row0+4..row0+7
    // y1 prefetch (consumed at the end of each p-phase)
    const unsigned y1A = y1p[(size_t)(row0 + 0 + half) * 32 + c2];
    const unsigned y1B = y1p[(size_t)(row0 + 2 + half) * 32 + c2];
    const unsigned y1C = y1p[(size_t)(row0 + 4 + half) * 32 + c2];
    const unsigned y1D = y1p[(size_t)(row0 + 6 + half) * 32 + c2];

    const unsigned sgn0 = (gamma[2 * c2]     >= 0.0f) ? 0x80000000u : 0u;
    const unsigned sgn1 = (gamma[2 * c2 + 1] >= 0.0f) ? 0x80000000u : 0u;
    const char* y2base = (const char*)y2p + (size_t)b * NDIM * 128;
    const unsigned coff = (unsigned)(c2 << 2);
    const int hb = half << 6;     // byte addr of this lane's source-lane base

    f32x2_t ssum = {0.f, 0.f};
    f32x2_t ssq  = {0.f, 0.f};

    #pragma unroll
    for (int t = 0; t < 2; ++t) {
        const int srci = t ? idx1 : idx0;
        const int ra = row0 + t * 4;         // pair0: rows ra, ra+1
        const int rb = ra + 2;               // pair1: rows rb, rb+1
        const unsigned y1u0 = t ? y1C : y1A;
        const unsigned y1u1 = t ? y1D : y1B;

        unsigned u0[KNB], u1[KNB];
        #pragma unroll
        for (int k = 0; k < KNB; ++k) {
            // row (ra+half)'s index k lives in lane half*16+k of srci
            int j = __builtin_amdgcn_ds_bpermute(hb + 4 * k, srci);
            u0[k] = *(const unsigned*)(y2base + ((((unsigned)j) << 7) + coff));
        }
        #pragma unroll
        for (int k = 0; k < KNB; ++k) {
            // row (rb+half)'s index k lives in lane 32+half*16+k
            int j = __builtin_amdgcn_ds_bpermute(128 + hb + 4 * k, srci);
            u1[k] = *(const unsigned*)(y2base + ((((unsigned)j) << 7) + coff));
        }

        #pragma unroll 2
        for (int p = 0; p < 2; ++p) {
            const unsigned* u = (p == 0) ? u0 : u1;
            const unsigned y1u = (p == 0) ? y1u0 : y1u1;
            const int rw = ((p == 0) ? ra : rb) + half;

            f32x2_t s2 = {0.f, 0.f};
            f32x2_t q2 = {0.f, 0.f};
            float M0 = -3.402823e38f, M1 = -3.402823e38f;
            #pragma unroll
            for (int k = 0; k < KNB; k += 2) {
                unsigned lo0 = u[k] << 16,     hi0 = u[k] & 0xffff0000u;
                unsigned lo1 = u[k + 1] << 16, hi1 = u[k + 1] & 0xffff0000u;
                f32x2_t v0 = { __uint_as_float(lo0), __uint_as_float(hi0) };
                f32x2_t v1 = { __uint_as_float(lo1), __uint_as_float(hi1) };
                s2 += v0;                                          // v_pk_add_f32
                q2 = __builtin_elementwise_fma(v0, v0, q2);        // v_pk_fma_f32
                s2 += v1;
                q2 = __builtin_elementwise_fma(v1, v1, q2);
                M0 = fmaxf(fmaxf(M0, __uint_as_float(lo0 ^ sgn0)),
                           __uint_as_float(lo1 ^ sgn0));           // v_max3_f32
                M1 = fmaxf(fmaxf(M1, __uint_as_float(hi0 ^ sgn1)),
                           __uint_as_float(hi1 ^ sgn1));
            }
            const f32x2_t y1v = { __uint_as_float(y1u << 16),
                                  __uint_as_float(y1u & 0xffff0000u) };
            const float h0 = y1v.x - __uint_as_float(__float_as_uint(M0) ^ sgn0);
            const float h1 = y1v.y - __uint_as_float(__float_as_uint(M1) ^ sgn1);
            hselp[(size_t)rw * 32 + c2] = pack_bf16(h0, h1);
            ssum += (f32x2_t){16.f, 16.f} * y1v - s2;
            ssq  += __builtin_elementwise_fma(
                        __builtin_elementwise_fma((f32x2_t){-2.f, -2.f}, s2,
                                                  (f32x2_t){16.f, 16.f} * y1v),
                        y1v, q2);
        }
    }

    __shared__ float rs[8][64];
    __shared__ float rq[8][64];
    rs[w * 2 + half][c2 * 2]     = ssum.x;
    rs[w * 2 + half][c2 * 2 + 1] = ssum.y;
    rq[w * 2 + half][c2 * 2]     = ssq.x;
    rq[w * 2 + half][c2 * 2 + 1] = ssq.y;
    __syncthreads();
    if (tid < 128) {
        const int c = tid & 63;
        float v = 0.f;
        if (tid < 64) { for (int r = 0; r < 8; ++r) v += rs[r][c]; }
        else          { for (int r = 0; r < 8; ++r) v += rq[r][c]; }
        atomicAdd(&statsN[(g & 31) * 128 + tid], v);   // striped: ~64 adds/line
    }
}

// ---------------- Kernel 3: reduce-in-prologue + affine + leaky + transpose ----------------
__global__ __launch_bounds__(256) void out_kernel(
    const unsigned* __restrict__ hselp,      // (B,N,32) bf16-pairs
    const float* __restrict__ statsN,        // (32,128)
    const float* __restrict__ gamma,
    const float* __restrict__ beta,
    float* __restrict__ out)                 // (B, 64, N)
{
    __shared__ float tile[64 * 65];
    __shared__ float colsum[128];
    __shared__ float sc[64], bi[64];
    const int tid = threadIdx.x;

    if (tid < 128) {
        float v = 0.f;
        #pragma unroll
        for (int i = 0; i < 32; ++i) v += statsN[i * 128 + tid];
        colsum[tid] = v;
    }
    __syncthreads();
    if (tid < 64) {
        float mean = colsum[tid] * (1.0f / BNK_F);
        float var  = colsum[64 + tid] * (1.0f / BNK_F) - mean * mean;
        float s    = gamma[tid] * rsqrtf(var + 1e-5f);
        sc[tid] = s;
        bi[tid] = beta[tid] - mean * s;
    }
    __syncthreads();

    const int b  = blockIdx.x >> 8;
    const int n0 = (blockIdx.x & 255) << 6;
    const size_t bn0 = (size_t)b * NDIM + n0;
    const int c4 = tid & 15;

    for (int r = tid >> 4; r < 64; r += 16) {
        uint2 u = *(const uint2*)&hselp[(bn0 + r) * 32 + c4 * 2];
        float v0 = fmaf(sc[4 * c4],     __uint_as_float(u.x << 16),         bi[4 * c4]);
        float v1 = fmaf(sc[4 * c4 + 1], __uint_as_float(u.x & 0xffff0000u), bi[4 * c4 + 1]);
        float v2 = fmaf(sc[4 * c4 + 2], __uint_as_float(u.y << 16),         bi[4 * c4 + 2]);
        float v3 = fmaf(sc[4 * c4 + 3], __uint_as_float(u.y & 0xffff0000u), bi[4 * c4 + 3]);
        v0 = (v0 >= 0.f) ? v0 : 0.2f * v0;
        v1 = (v1 >= 0.f) ? v1 : 0.2f * v1;
        v2 = (v2 >= 0.f) ? v2 : 0.2f * v2;
        v3 = (v3 >= 0.f) ? v3 : 0.2f * v3;
        tile[r * 65 + 4 * c4]     = v0;
        tile[r * 65 + 4 * c4 + 1] = v1;
        tile[r * 65 + 4 * c4 + 2] = v2;
        tile[r * 65 + 4 * c4 + 3] = v3;
    }
    __syncthreads();
    const int ln = tid & 15;
    for (int o = tid >> 4; o < 64; o += 16) {
        f32x4_t v;
        v[0] = tile[(ln * 4 + 0) * 65 + o];
        v[1] = tile[(ln * 4 + 1) * 65 + o];
        v[2] = tile[(ln * 4 + 2) * 65 + o];
        v[3] = tile[(ln * 4 + 3) * 65 + o];
        *(f32x4_t*)&out[((size_t)(b * 64 + o) << 14) + n0 + ln * 4] = v;
    }
}

extern "C" void kernel_launch(void* const* d_in, const int* in_sizes, int n_in,
                              void* d_out, int out_size, void* d_ws, size_t ws_size,
                              hipStream_t stream) {
    const float* x     = (const float*)d_in[0];
    const int*   ei    = (const int*)d_in[1];
    const float* W     = (const float*)d_in[2];
    const float* gamma = (const float*)d_in[3];
    const float* beta  = (const float*)d_in[4];
    float* out = (float*)d_out;

    char* ws = (char*)d_ws;
    unsigned* y1p    = (unsigned*)(ws);                       // 8 MiB (bf16 pairs)
    unsigned* y2p    = (unsigned*)(ws + 8388608);             // 8 MiB
    unsigned* hselp  = (unsigned*)(ws + 16777216);            // 8 MiB
    float*    statsN = (float*)(ws + 25165824);               // 16 KiB (32x128)

    gemm_mfma_kernel <<<dim3(1024), dim3(256), 0, stream>>>(x, W, y1p, y2p, statsN);
    gather_kernel    <<<dim3(2048), dim3(256), 0, stream>>>(y1p, y2p, ei, gamma, hselp, statsN);
    out_kernel       <<<dim3(1024), dim3(256), 0, stream>>>(hselp, statsN, gamma, beta, out);
}